// Round 3
// baseline (24980.745 us; speedup 1.0000x reference)
//
#include <hip/hip_runtime.h>
#include <math.h>

// ---------------------------------------------------------------------------
// MDN-RNN round 3: single persistent kernel, grid barrier per timestep.
//   grid = 256 WGs x 512 threads, 1 WG/CU (102 KB LDS forces it), all
//   co-resident -> custom atomic-counter grid barrier.
//   WG (ut,bt): LSTM u-tile 16 x b-tile 16, k split in halves across tid>>8.
//   WG w also owns MDN head for batch b = w (hid1/hid2/o in LDS, WG-local).
//   Cross-WG data: ONLY h (ping-pong in ws), via AGENT-scope atomics
//   (write-through / cache-bypassing) so no cache flush per step needed.
//   c state lives in registers for the whole sequence.
// Pipeline lags (same as rounds 1-2): at iter s:
//   LSTM: h_{s+1} (s<=1022) | L1: h_s (1<=s<=1023) | L2 (2<=s<=1024)
//   L3 (3<=s<=1025) | FIN -> out t=s-4 (4<=s<=1026)
// ---------------------------------------------------------------------------

#define NOUT  1023
#define KK    5

// ws layout (floats)
#define OFF_H    0            // 2 x 65536 ping-pong h[par][unit][b]
#define OFF_CNT  131072       // barrier counter (64 floats reserved)
#define OFF_WHH  131136       // float4[65536]: Wg_hh[k][u][4g]
#define OFF_WIH  393280       // float4[8960] : Wg_ih[j][u][4g]
#define OFF_BG   429120       // float4[256]  : bias[u][4g]
#define OFF_W1T  430144       // [256k][128ch]
#define OFF_W2T  462912       // [100k][128ch]
#define OFF_W3T  475712       // [100k][192ch]
// total 494,912 floats = 1.98 MB

#define MEANBASE (256 * NOUT * KK)
#define VARBASE  (MEANBASE + 256 * NOUT * KK * 32)

__device__ __forceinline__ float sigf(float x) { return 1.0f / (1.0f + expf(-x)); }

// --------------------------- one-time weight pack ---------------------------
__global__ __launch_bounds__(256) void prep_pack(
    const float* __restrict__ W_ih, const float* __restrict__ W_hh,
    const float* __restrict__ b_ih, const float* __restrict__ b_hh,
    const float* __restrict__ W1,   const float* __restrict__ W2,
    const float* __restrict__ W3,   float* __restrict__ ws)
{
    const int idx = blockIdx.x * 256 + threadIdx.x;
    if (idx < 65536) {
        int k = idx >> 8, u = idx & 255;
        float4 v;
        v.x = W_hh[(0 * 256 + u) * 256 + k];
        v.y = W_hh[(1 * 256 + u) * 256 + k];
        v.z = W_hh[(2 * 256 + u) * 256 + k];
        v.w = W_hh[(3 * 256 + u) * 256 + k];
        ((float4*)(ws + OFF_WHH))[idx] = v;
    } else if (idx < 74496) {
        int r = idx - 65536;
        int j = r >> 8, u = r & 255;
        float4 v;
        v.x = W_ih[(0 * 256 + u) * 35 + j];
        v.y = W_ih[(1 * 256 + u) * 35 + j];
        v.z = W_ih[(2 * 256 + u) * 35 + j];
        v.w = W_ih[(3 * 256 + u) * 35 + j];
        ((float4*)(ws + OFF_WIH))[r] = v;
    } else if (idx < 74752) {
        int u = idx - 74496;
        float4 v;
        v.x = b_ih[0 * 256 + u] + b_hh[0 * 256 + u];
        v.y = b_ih[1 * 256 + u] + b_hh[1 * 256 + u];
        v.z = b_ih[2 * 256 + u] + b_hh[2 * 256 + u];
        v.w = b_ih[3 * 256 + u] + b_hh[3 * 256 + u];
        ((float4*)(ws + OFF_BG))[u] = v;
    } else if (idx < 107520) {
        int r = idx - 74752;
        int k = r >> 7, c = r & 127;
        if (c < 100) ws[OFF_W1T + k * 128 + c] = W1[c * 256 + k];
    } else if (idx < 120320) {
        int r = idx - 107520;
        int k = r >> 7, c = r & 127;
        if (c < 100) ws[OFF_W2T + k * 128 + c] = W2[c * 100 + k];
    } else if (idx < 139520) {
        int r = idx - 120320;
        int k = r / 192, c = r - k * 192;
        if (c < 170) ws[OFF_W3T + k * 192 + c] = W3[c * 100 + k];
    }
}

// ------------------------------ persistent kernel ---------------------------
__global__ __launch_bounds__(512, 1) void mdn_rnn_persist(
    const float* __restrict__ x,
    const float* __restrict__ b1, const float* __restrict__ b2,
    const float* __restrict__ b3,
    float* __restrict__ ws, float* __restrict__ out)
{
    __shared__ float4 wlds[256][16];   // 64 KB  Wg_hh slice
    __shared__ float4 xlds[35][16];    // 8.75 KB Wg_ih slice
    __shared__ float4 bg[16];
    __shared__ float  hlds[256][16];   // 16 KB  h stage for LSTM
    __shared__ float  hcol[256];       // 1 KB   h column for head (b = wg)
    __shared__ float4 pg[256];         // 4 KB   LSTM khi partials
    __shared__ float  ph1[4][104];
    __shared__ float  ph2[4][104];
    __shared__ float  ph3[176];
    __shared__ float  hid1L[2][104];
    __shared__ float  hid2L[2][104];
    __shared__ float  oL[2][176];

    const int tid = threadIdx.x;
    const int wg  = blockIdx.x;
    const int u0  = (wg >> 4) * 16;
    const int b0  = (wg & 15) * 16;
    const int half = tid >> 8;          // 0: k-lo, 1: k-hi
    const int ul   = (tid >> 4) & 15;
    const int bl   = tid & 15;
    const int bb   = b0 + bl;
    const int q    = tid >> 7;          // quarter for head k-split
    const int l    = tid & 127;
    const int l3   = tid & 255;

    const float4* Wg4 = (const float4*)(ws + OFF_WHH);
    const float4* Wx4 = (const float4*)(ws + OFF_WIH);
    const float4* Bg4 = (const float4*)(ws + OFF_BG);
    const float*  W1T = ws + OFF_W1T;
    const float*  W2T = ws + OFF_W2T;
    const float*  W3T = ws + OFF_W3T;
    float* hbuf = ws + OFF_H;
    unsigned* cnt = (unsigned*)(ws + OFF_CNT);

    // stage weights into LDS once
    for (int i = tid; i < 4096; i += 512)
        wlds[i >> 4][i & 15] = Wg4[(i >> 4) * 256 + u0 + (i & 15)];
    for (int i = tid; i < 560; i += 512)
        xlds[i >> 4][i & 15] = Wx4[(i >> 4) * 256 + u0 + (i & 15)];
    if (tid < 16) bg[tid] = Bg4[u0 + tid];
    __syncthreads();

    float c_reg = 0.0f;

    for (int s = 0; s < 1027; ++s) {
        const int parC = s & 1;
        const int parN = parC ^ 1;

        // ---------------- stage phase (agent-scope reads of h) -------------
        if (s <= 1022) {
            const int row = tid >> 1, hf = tid & 1;
            const float* src = hbuf + parC * 65536 + row * 256 + b0 + hf * 8;
            float v[8];
            #pragma unroll
            for (int i = 0; i < 8; ++i)
                v[i] = __hip_atomic_load(src + i, __ATOMIC_RELAXED,
                                         __HIP_MEMORY_SCOPE_AGENT);
            #pragma unroll
            for (int i = 0; i < 8; ++i) hlds[row][hf * 8 + i] = v[i];
        }
        if (s >= 1 && s <= 1023 && tid < 256)
            hcol[tid] = __hip_atomic_load(hbuf + parC * 65536 + tid * 256 + wg,
                                          __ATOMIC_RELAXED, __HIP_MEMORY_SCOPE_AGENT);
        __syncthreads();

        // ---------------- partial phase ------------------------------------
        float4 acc = make_float4(0.f, 0.f, 0.f, 0.f);
        if (s <= 1022) {
            const int k0 = half * 128;
            #pragma unroll 8
            for (int k = 0; k < 128; ++k) {
                float  hv = hlds[k0 + k][bl];
                float4 w  = wlds[k0 + k][ul];
                acc.x = fmaf(w.x, hv, acc.x);
                acc.y = fmaf(w.y, hv, acc.y);
                acc.z = fmaf(w.z, hv, acc.z);
                acc.w = fmaf(w.w, hv, acc.w);
            }
            const float* xr = x + (size_t)bb * (1024 * 35) + (size_t)s * 35;
            if (half == 0) {
                #pragma unroll
                for (int j = 0; j < 18; ++j) {
                    float  xv = xr[j];
                    float4 w  = xlds[j][ul];
                    acc.x = fmaf(w.x, xv, acc.x);
                    acc.y = fmaf(w.y, xv, acc.y);
                    acc.z = fmaf(w.z, xv, acc.z);
                    acc.w = fmaf(w.w, xv, acc.w);
                }
            } else {
                #pragma unroll
                for (int j = 18; j < 35; ++j) {
                    float  xv = xr[j];
                    float4 w  = xlds[j][ul];
                    acc.x = fmaf(w.x, xv, acc.x);
                    acc.y = fmaf(w.y, xv, acc.y);
                    acc.z = fmaf(w.z, xv, acc.z);
                    acc.w = fmaf(w.w, xv, acc.w);
                }
                pg[tid - 256] = acc;
            }
        }
        // L1 partials: k quarters of 64
        if (s >= 1 && s <= 1023 && l < 100) {
            float a1 = 0.f;
            const int kb = q * 64;
            #pragma unroll 8
            for (int k = 0; k < 64; ++k)
                a1 = fmaf(W1T[(kb + k) * 128 + l], hcol[kb + k], a1);
            ph1[q][l] = a1;
        }
        // L2 partials: k quarters of 25
        if (s >= 2 && s <= 1024 && l < 100) {
            float a2 = 0.f;
            const int kb = q * 25;
            #pragma unroll 5
            for (int k = 0; k < 25; ++k)
                a2 = fmaf(W2T[(kb + k) * 128 + l], hid1L[parN][kb + k], a2);
            ph2[q][l] = a2;
        }
        // L3 partials: k halves of 50
        float a3 = 0.f;
        if (s >= 3 && s <= 1025 && l3 < 170) {
            const int kb = half * 50;
            #pragma unroll 5
            for (int k = 0; k < 50; ++k)
                a3 = fmaf(W3T[(kb + k) * 192 + l3], hid2L[parN][kb + k], a3);
            if (half) ph3[l3] = a3;
        }
        // FIN (reads prev-iter o parity): threads 342..511 -> ch 0..169
        if (s >= 4 && tid >= 342) {
            const int lf = tid - 342;
            const int t  = s - 4;
            float m = oL[parN][0];
            #pragma unroll
            for (int k = 1; k < KK; ++k) m = fmaxf(m, oL[parN][k]);
            float den = 0.f;
            #pragma unroll
            for (int k = 0; k < KK; ++k) den += expf(oL[parN][k] - m);
            float v = oL[parN][lf];
            if (lf < KK) {
                out[(size_t)wg * (NOUT * KK) + (size_t)t * KK + lf] =
                    expf(v - m) / den;
            } else if (lf < 2 * KK) {
                out[VARBASE + (size_t)wg * (NOUT * KK) + (size_t)t * KK + (lf - KK)] =
                    expf(v);
            } else {
                out[MEANBASE + ((size_t)wg * NOUT + t) * 160 + (lf - 2 * KK)] = v;
            }
        }
        __syncthreads();

        // ---------------- finalize phase -----------------------------------
        if (s <= 1022 && half == 0) {
            float4 p = pg[tid];
            float4 bgv = bg[ul];
            float gi = acc.x + p.x + bgv.x;
            float gf = acc.y + p.y + bgv.y;
            float gg = acc.z + p.z + bgv.z;
            float go = acc.w + p.w + bgv.w;
            float iv = sigf(gi), fv = sigf(gf), gv = tanhf(gg), ov = sigf(go);
            c_reg = fv * c_reg + iv * gv;
            float hval = ov * tanhf(c_reg);
            __hip_atomic_store(hbuf + parN * 65536 + (u0 + ul) * 256 + bb, hval,
                               __ATOMIC_RELAXED, __HIP_MEMORY_SCOPE_AGENT);
        }
        if (s >= 1 && s <= 1023 && tid >= 256 && tid < 356) {
            const int c = tid - 256;
            float v = ph1[0][c] + ph1[1][c] + ph1[2][c] + ph1[3][c] + b1[c];
            hid1L[parC][c] = fmaxf(v, 0.f);
        }
        if (s >= 2 && s <= 1024 && tid >= 356 && tid < 456) {
            const int c = tid - 356;
            float v = ph2[0][c] + ph2[1][c] + ph2[2][c] + ph2[3][c] + b2[c];
            hid2L[parC][c] = fmaxf(v, 0.f);
        }
        if (s >= 3 && s <= 1025 && half == 0 && tid < 170)
            oL[parC][tid] = a3 + ph3[tid] + b3[tid];

        // ---------------- grid barrier -------------------------------------
        if (s < 1026) {
            __syncthreads();
            if (tid == 0) {
                __hip_atomic_fetch_add(cnt, 1u, __ATOMIC_RELEASE,
                                       __HIP_MEMORY_SCOPE_AGENT);
                const unsigned target = (unsigned)(s + 1) * 256u;
                while (__hip_atomic_load(cnt, __ATOMIC_ACQUIRE,
                                         __HIP_MEMORY_SCOPE_AGENT) < target)
                    __builtin_amdgcn_s_sleep(2);
            }
            __syncthreads();
        }
    }
}

extern "C" void kernel_launch(void* const* d_in, const int* in_sizes, int n_in,
                              void* d_out, int out_size, void* d_ws, size_t ws_size,
                              hipStream_t stream)
{
    const float* x    = (const float*)d_in[0];
    const float* W_ih = (const float*)d_in[1];
    const float* W_hh = (const float*)d_in[2];
    const float* b_ih = (const float*)d_in[3];
    const float* b_hh = (const float*)d_in[4];
    const float* W1   = (const float*)d_in[5];
    const float* b1   = (const float*)d_in[6];
    const float* W2   = (const float*)d_in[7];
    const float* b2   = (const float*)d_in[8];
    const float* W3   = (const float*)d_in[9];
    const float* b3   = (const float*)d_in[10];
    float* out = (float*)d_out;
    float* ws  = (float*)d_ws;

    hipMemsetAsync(ws + OFF_H,   0, 65536 * sizeof(float), stream); // h parity 0
    hipMemsetAsync(ws + OFF_CNT, 0, 64 * sizeof(float), stream);    // barrier cnt
    prep_pack<<<545, 256, 0, stream>>>(W_ih, W_hh, b_ih, b_hh, W1, W2, W3, ws);
    mdn_rnn_persist<<<256, 512, 0, stream>>>(x, b1, b2, b3, ws, out);
}

// Round 4
// 13390.491 us; speedup vs baseline: 1.8656x; 1.8656x over previous
//
#include <hip/hip_runtime.h>
#include <math.h>

// ---------------------------------------------------------------------------
// MDN-RNN round 4: persistent kernel, RELAXED-ONLY cross-WG sync (no acquire/
// release fences -> no per-step L2 invalidation), flag-array grid barrier,
// b128-tiled LSTM k-loop, x prefetched one step ahead.
//
// grid = 256 WGs x 512 threads, 1 WG/CU (148 KB LDS).
// WG (ut=wg>>4, bt=wg&15): units u0..u0+15, batches b0..b0+15.
// LSTM partial tile: thread = (ul 16) x (kq 8: 32-k slice) x (bq 4: 4 batches)
//   per k: 1 ds_read_b128 (W gate-quad) + 1 ds_read_b128 (h batch-quad) ->
//   16 FMA. Partials p4[kq][ul][b] reduced by finalize threads (u,b).
// Head (batch b = wg): L1/L2/L3/FIN pipelined at lags 1..4, WG-local LDS.
// Cross-WG data: ONLY h (ping-pong in ws) via relaxed agent atomics (sc0 sc1,
// coherence-point access, no cache maintenance).
// ---------------------------------------------------------------------------

#define NOUT  1023
#define KK    5

// ws layout (floats)
#define OFF_H    0            // 2 x 65536 ping-pong h[par][u][b]
#define OFF_FLG  131072       // 256 uint flags (barrier), padded to 64 floats
#define OFF_WHH  131136       // float4[65536]: Wg_hh[k][u][4g]
#define OFF_WIH  393280       // float4[8960] : Wg_ih[j][u][4g]
#define OFF_BG   429120       // float4[256]  : bias[u][4g]
#define OFF_W1T  430144       // [256k][128ch]
#define OFF_W2T  462912       // [100k][128ch]
#define OFF_W3T  475712       // [100k][192ch]

#define MEANBASE (256 * NOUT * KK)
#define VARBASE  (MEANBASE + 256 * NOUT * KK * 32)

__device__ __forceinline__ float sigf(float x) { return 1.0f / (1.0f + expf(-x)); }

// --------------------------- one-time weight pack ---------------------------
__global__ __launch_bounds__(256) void prep_pack(
    const float* __restrict__ W_ih, const float* __restrict__ W_hh,
    const float* __restrict__ b_ih, const float* __restrict__ b_hh,
    const float* __restrict__ W1,   const float* __restrict__ W2,
    const float* __restrict__ W3,   float* __restrict__ ws)
{
    const int idx = blockIdx.x * 256 + threadIdx.x;
    if (idx < 65536) {
        int k = idx >> 8, u = idx & 255;
        float4 v;
        v.x = W_hh[(0 * 256 + u) * 256 + k];
        v.y = W_hh[(1 * 256 + u) * 256 + k];
        v.z = W_hh[(2 * 256 + u) * 256 + k];
        v.w = W_hh[(3 * 256 + u) * 256 + k];
        ((float4*)(ws + OFF_WHH))[idx] = v;
    } else if (idx < 74496) {
        int r = idx - 65536;
        int j = r >> 8, u = r & 255;
        float4 v;
        v.x = W_ih[(0 * 256 + u) * 35 + j];
        v.y = W_ih[(1 * 256 + u) * 35 + j];
        v.z = W_ih[(2 * 256 + u) * 35 + j];
        v.w = W_ih[(3 * 256 + u) * 35 + j];
        ((float4*)(ws + OFF_WIH))[r] = v;
    } else if (idx < 74752) {
        int u = idx - 74496;
        float4 v;
        v.x = b_ih[0 * 256 + u] + b_hh[0 * 256 + u];
        v.y = b_ih[1 * 256 + u] + b_hh[1 * 256 + u];
        v.z = b_ih[2 * 256 + u] + b_hh[2 * 256 + u];
        v.w = b_ih[3 * 256 + u] + b_hh[3 * 256 + u];
        ((float4*)(ws + OFF_BG))[u] = v;
    } else if (idx < 107520) {
        int r = idx - 74752;
        int k = r >> 7, c = r & 127;
        if (c < 100) ws[OFF_W1T + k * 128 + c] = W1[c * 256 + k];
    } else if (idx < 120320) {
        int r = idx - 107520;
        int k = r >> 7, c = r & 127;
        if (c < 100) ws[OFF_W2T + k * 128 + c] = W2[c * 100 + k];
    } else if (idx < 139520) {
        int r = idx - 120320;
        int k = r / 192, c = r - k * 192;
        if (c < 170) ws[OFF_W3T + k * 192 + c] = W3[c * 100 + k];
    }
}

// ------------------------------ persistent kernel ---------------------------
__global__ __launch_bounds__(512, 1) void mdn_rnn_persist(
    const float* __restrict__ x,
    const float* __restrict__ b1, const float* __restrict__ b2,
    const float* __restrict__ b3,
    float* __restrict__ ws, float* __restrict__ out)
{
    // LDS ~148.5 KB total
    __shared__ float4 wlds4[4360];      // W_hh slice: idx = k*17 + ul + (k>>5)
    __shared__ float4 xlds4[595];       // W_ih slice: idx = j*17 + ul
    __shared__ float4 bg[16];
    __shared__ float  hlds[5120];       // h: [u][20] XOR-swizzled cols
    __shared__ float  xst[2][700];      // x ping-pong: [j][20]
    __shared__ float4 p4[2176];         // LSTM partials [kq*16+ul][17 cols]
    __shared__ float  hcol[256];
    __shared__ float  ph1[4][104];
    __shared__ float  ph2[4][104];
    __shared__ float  ph3[176];
    __shared__ float  hid1L[2][104];
    __shared__ float  hid2L[2][104];
    __shared__ float  oL[2][176];

    const int tid = threadIdx.x;
    const int wg  = blockIdx.x;
    const int u0  = (wg >> 4) * 16;
    const int b0  = (wg & 15) * 16;

    // LSTM partial tile
    const int ul   = tid & 15;
    const int kq   = (tid >> 4) & 7;
    const int bq   = tid >> 7;
    const int hswz = 4 * (bq ^ (kq & 3));
    const int joff = (kq < 3) ? kq * 5 : 15 + (kq - 3) * 4;
    const int jcnt = (kq < 3) ? 5 : 4;
    // head tile
    const int q = tid >> 7, l = tid & 127, l3 = tid & 255, half = tid >> 8;
    // finalize tile (tid < 256)
    const int fbl = tid & 15, ful = tid >> 4;
    // x prefetch mapping (tid < 280: elements 2*tid, 2*tid+1 of 16x35)
    const int e0 = tid * 2,  pb0 = e0 / 35, pj0 = e0 - pb0 * 35;
    const int e1 = e0 + 1,   pb1 = e1 / 35, pj1 = e1 - pb1 * 35;

    const float4* Wg4 = (const float4*)(ws + OFF_WHH);
    const float4* Wx4 = (const float4*)(ws + OFF_WIH);
    const float*  W1T = ws + OFF_W1T;
    const float*  W2T = ws + OFF_W2T;
    const float*  W3T = ws + OFF_W3T;
    float* hbuf = ws + OFF_H;
    unsigned* flags = (unsigned*)(ws + OFF_FLG);

    // ---- one-time staging ----
    for (int i = tid; i < 4096; i += 512) {
        int k = i >> 4, uu = i & 15;
        wlds4[k * 17 + uu + (k >> 5)] = Wg4[k * 256 + u0 + uu];
    }
    for (int i = tid; i < 560; i += 512) {
        int j = i >> 4, uu = i & 15;
        xlds4[j * 17 + uu] = Wx4[j * 256 + u0 + uu];
    }
    if (tid < 16) bg[tid] = ((const float4*)(ws + OFF_BG))[u0 + tid];
    if (tid < 280) {
        xst[0][pj0 * 20 + pb0] = x[(size_t)(b0 + pb0) * 35840 + pj0];
        xst[0][pj1 * 20 + pb1] = x[(size_t)(b0 + pb1) * 35840 + pj1];
    }
    __syncthreads();

    float c_reg = 0.0f;

    for (int s = 0; s < 1027; ++s) {
        const int parC = s & 1;
        const int parN = parC ^ 1;

        // ---- x prefetch issue (plain cached loads; land during k-loop) ----
        float xpf0 = 0.f, xpf1 = 0.f;
        const bool dopf = (s < 1022) && (tid < 280);
        if (dopf) {
            const float* xp = x + (size_t)(s + 1) * 35;
            xpf0 = xp[(size_t)(b0 + pb0) * 35840 + pj0];
            xpf1 = xp[(size_t)(b0 + pb1) * 35840 + pj1];
        }

        // ---- stage h (relaxed agent loads, b64-vectorized) ----
        if (s <= 1022) {
            const int su = tid >> 1, shf = tid & 1;
            const unsigned long long* src = (const unsigned long long*)
                (hbuf + parC * 65536 + su * 256 + b0 + shf * 8);
            unsigned long long v[4];
            #pragma unroll
            for (int i = 0; i < 4; ++i)
                v[i] = __hip_atomic_load(src + i, __ATOMIC_RELAXED,
                                         __HIP_MEMORY_SCOPE_AGENT);
            const int m = (su >> 5) & 3;
            #pragma unroll
            for (int i = 0; i < 4; ++i) {
                int c   = shf * 8 + i * 2;
                int col = ((c >> 2) ^ m) * 4 + (c & 3);
                float2 f2;
                f2.x = __uint_as_float((unsigned)v[i]);
                f2.y = __uint_as_float((unsigned)(v[i] >> 32));
                *(float2*)&hlds[su * 20 + col] = f2;
            }
        }
        if (s >= 1 && s <= 1023 && tid < 256)
            hcol[tid] = __hip_atomic_load(hbuf + parC * 65536 + tid * 256 + wg,
                                          __ATOMIC_RELAXED, __HIP_MEMORY_SCOPE_AGENT);
        __syncthreads();

        // ---- LSTM partial: 32 k-iters, b128-only LDS ----
        if (s <= 1022) {
            float4 acc0 = make_float4(0.f, 0.f, 0.f, 0.f);
            float4 acc1 = acc0, acc2 = acc0, acc3 = acc0;
            const int kb = kq * 32;
            #pragma unroll 8
            for (int kk = 0; kk < 32; ++kk) {
                const int k  = kb + kk;
                float4 w  = wlds4[k * 17 + ul + kq];
                float4 hv = *(const float4*)&hlds[k * 20 + hswz];
                acc0.x = fmaf(w.x, hv.x, acc0.x); acc0.y = fmaf(w.y, hv.x, acc0.y);
                acc0.z = fmaf(w.z, hv.x, acc0.z); acc0.w = fmaf(w.w, hv.x, acc0.w);
                acc1.x = fmaf(w.x, hv.y, acc1.x); acc1.y = fmaf(w.y, hv.y, acc1.y);
                acc1.z = fmaf(w.z, hv.y, acc1.z); acc1.w = fmaf(w.w, hv.y, acc1.w);
                acc2.x = fmaf(w.x, hv.z, acc2.x); acc2.y = fmaf(w.y, hv.z, acc2.y);
                acc2.z = fmaf(w.z, hv.z, acc2.z); acc2.w = fmaf(w.w, hv.z, acc2.w);
                acc3.x = fmaf(w.x, hv.w, acc3.x); acc3.y = fmaf(w.y, hv.w, acc3.y);
                acc3.z = fmaf(w.z, hv.w, acc3.z); acc3.w = fmaf(w.w, hv.w, acc3.w);
            }
            const float* xsrc = xst[parC];
            for (int jj = 0; jj < jcnt; ++jj) {
                const int j = joff + jj;
                float4 w  = xlds4[j * 17 + ul];
                float4 xv = *(const float4*)&xsrc[j * 20 + bq * 4];
                acc0.x = fmaf(w.x, xv.x, acc0.x); acc0.y = fmaf(w.y, xv.x, acc0.y);
                acc0.z = fmaf(w.z, xv.x, acc0.z); acc0.w = fmaf(w.w, xv.x, acc0.w);
                acc1.x = fmaf(w.x, xv.y, acc1.x); acc1.y = fmaf(w.y, xv.y, acc1.y);
                acc1.z = fmaf(w.z, xv.y, acc1.z); acc1.w = fmaf(w.w, xv.y, acc1.w);
                acc2.x = fmaf(w.x, xv.z, acc2.x); acc2.y = fmaf(w.y, xv.z, acc2.y);
                acc2.z = fmaf(w.z, xv.z, acc2.z); acc2.w = fmaf(w.w, xv.z, acc2.w);
                acc3.x = fmaf(w.x, xv.w, acc3.x); acc3.y = fmaf(w.y, xv.w, acc3.y);
                acc3.z = fmaf(w.z, xv.w, acc3.z); acc3.w = fmaf(w.w, xv.w, acc3.w);
            }
            const int r = (kq * 16 + ul) * 17 + bq * 4;
            p4[r + 0] = acc0; p4[r + 1] = acc1; p4[r + 2] = acc2; p4[r + 3] = acc3;
        }

        // ---- head partials (WG-local, cached global weight reads) ----
        if (s >= 1 && s <= 1023 && l < 100) {
            float a1 = 0.f;
            const int kb1 = q * 64;
            #pragma unroll 8
            for (int k = 0; k < 64; ++k)
                a1 = fmaf(W1T[(kb1 + k) * 128 + l], hcol[kb1 + k], a1);
            ph1[q][l] = a1;
        }
        if (s >= 2 && s <= 1024 && l < 100) {
            float a2 = 0.f;
            const int kb2 = q * 25;
            #pragma unroll 5
            for (int k = 0; k < 25; ++k)
                a2 = fmaf(W2T[(kb2 + k) * 128 + l], hid1L[parN][kb2 + k], a2);
            ph2[q][l] = a2;
        }
        float a3 = 0.f;
        if (s >= 3 && s <= 1025 && l3 < 170) {
            const int kb3 = half * 50;
            #pragma unroll 5
            for (int k = 0; k < 50; ++k)
                a3 = fmaf(W3T[(kb3 + k) * 192 + l3], hid2L[parN][kb3 + k], a3);
            if (half) ph3[l3] = a3;
        }
        if (s >= 4 && tid >= 342) {
            const int lf = tid - 342;
            const int t  = s - 4;
            float m5 = oL[parN][0];
            #pragma unroll
            for (int k = 1; k < KK; ++k) m5 = fmaxf(m5, oL[parN][k]);
            float den = 0.f;
            #pragma unroll
            for (int k = 0; k < KK; ++k) den += expf(oL[parN][k] - m5);
            float v = oL[parN][lf];
            if (lf < KK) {
                out[(size_t)wg * (NOUT * KK) + (size_t)t * KK + lf] =
                    expf(v - m5) / den;
            } else if (lf < 2 * KK) {
                out[VARBASE + (size_t)wg * (NOUT * KK) + (size_t)t * KK + (lf - KK)] =
                    expf(v);
            } else {
                out[MEANBASE + ((size_t)wg * NOUT + t) * 160 + (lf - 2 * KK)] = v;
            }
        }
        __syncthreads();

        // ---- finalize ----
        if (s <= 1022 && tid < 256) {
            float4 g = bg[ful];
            #pragma unroll
            for (int k2 = 0; k2 < 8; ++k2) {
                float4 p = p4[(k2 * 16 + ful) * 17 + fbl];
                g.x += p.x; g.y += p.y; g.z += p.z; g.w += p.w;
            }
            float iv = sigf(g.x), fv = sigf(g.y), gv = tanhf(g.z), ov = sigf(g.w);
            c_reg = fv * c_reg + iv * gv;
            float hval = ov * tanhf(c_reg);
            __hip_atomic_store(hbuf + parN * 65536 + (u0 + ful) * 256 + (b0 + fbl),
                               hval, __ATOMIC_RELAXED, __HIP_MEMORY_SCOPE_AGENT);
        }
        if (s >= 1 && s <= 1023 && tid >= 256 && tid < 356) {
            const int c = tid - 256;
            float v = ph1[0][c] + ph1[1][c] + ph1[2][c] + ph1[3][c] + b1[c];
            hid1L[parC][c] = fmaxf(v, 0.f);
        }
        if (s >= 2 && s <= 1024 && tid >= 356 && tid < 456) {
            const int c = tid - 356;
            float v = ph2[0][c] + ph2[1][c] + ph2[2][c] + ph2[3][c] + b2[c];
            hid2L[parC][c] = fmaxf(v, 0.f);
        }
        if (s >= 3 && s <= 1025 && half == 0 && tid < 170)
            oL[parC][tid] = a3 + ph3[tid] + b3[tid];
        if (dopf) {
            xst[parN][pj0 * 20 + pb0] = xpf0;
            xst[parN][pj1 * 20 + pb1] = xpf1;
        }

        // ---- grid barrier: relaxed flag array, NO fences ----
        if (s < 1026) {
            __syncthreads();   // drains each wave's vmcnt before s_barrier
            if (tid == 0)
                __hip_atomic_store(&flags[wg], (unsigned)(s + 1),
                                   __ATOMIC_RELAXED, __HIP_MEMORY_SCOPE_AGENT);
            if (tid < 64) {
                const unsigned tgt = (unsigned)(s + 1);
                for (;;) {
                    unsigned ok = 1;
                    #pragma unroll
                    for (int j2 = 0; j2 < 4; ++j2) {
                        unsigned v = __hip_atomic_load(&flags[tid + 64 * j2],
                                         __ATOMIC_RELAXED, __HIP_MEMORY_SCOPE_AGENT);
                        ok &= (unsigned)(v >= tgt);
                    }
                    if (__all((int)ok)) break;
                    __builtin_amdgcn_s_sleep(2);
                }
            }
            asm volatile("" ::: "memory");
            __syncthreads();
        }
    }
}

extern "C" void kernel_launch(void* const* d_in, const int* in_sizes, int n_in,
                              void* d_out, int out_size, void* d_ws, size_t ws_size,
                              hipStream_t stream)
{
    const float* x    = (const float*)d_in[0];
    const float* W_ih = (const float*)d_in[1];
    const float* W_hh = (const float*)d_in[2];
    const float* b_ih = (const float*)d_in[3];
    const float* b_hh = (const float*)d_in[4];
    const float* W1   = (const float*)d_in[5];
    const float* b1   = (const float*)d_in[6];
    const float* W2   = (const float*)d_in[7];
    const float* b2   = (const float*)d_in[8];
    const float* W3   = (const float*)d_in[9];
    const float* b3   = (const float*)d_in[10];
    float* out = (float*)d_out;
    float* ws  = (float*)d_ws;

    hipMemsetAsync(ws + OFF_H,   0, 65536 * sizeof(float), stream); // h parity 0
    hipMemsetAsync(ws + OFF_FLG, 0, 256 * sizeof(unsigned), stream); // flags
    prep_pack<<<545, 256, 0, stream>>>(W_ih, W_hh, b_ih, b_hh, W1, W2, W3, ws);
    mdn_rnn_persist<<<256, 512, 0, stream>>>(x, b1, b2, b3, ws, out);
}

// Round 5
// 11865.340 us; speedup vs baseline: 2.1054x; 1.1285x over previous
//
#include <hip/hip_runtime.h>
#include <math.h>

// ---------------------------------------------------------------------------
// MDN-RNN round 5: persistent kernel, NO global barrier.
// Cluster = the 16 WGs with equal g = wg&15 (same batch group, same XCD for
// round-robin dispatch). They are the only producers AND consumers of their
// h-slice -> producer-publish / consumer-poll protocol:
//   E: store h slice (relaxed agent atomics) -> __syncthreads (vmcnt drain)
//      -> publish flags[g][ut] = s+1
//   next iter: poll 16 cluster flags >= s, then stage h from global.
// Flag gating also protects ping-pong reuse (peer published h_s => peer
// already consumed h_{s-1} from the slot being overwritten).
// Head (batch g*16+ut, WG-local): L2/L3/FIN run BEFORE the poll (overlap),
// L1 runs with the LSTM k-loop reading h column from the staged LDS tile.
// coeff/var outputs batched 8 steps in LDS -> contiguous 160B flushes.
// ---------------------------------------------------------------------------

#define NOUT  1023
#define KK    5

// ws layout (floats)
#define OFF_H    0            // 2 x 65536 ping-pong h[par][u][b]
#define OFF_FLG  131072       // 256 uint publish flags [g16][ut16]
#define OFF_WHH  131136       // float4[65536]: Wg_hh[k][u][4g]
#define OFF_WIH  393280       // float4[8960] : Wg_ih[j][u][4g]
#define OFF_BG   429120       // float4[256]  : bias[u][4g]
#define OFF_W1T  430144       // [256k][128ch]
#define OFF_W2T  462912       // [100k][128ch]
#define OFF_W3T  475712       // [100k][192ch]

#define MEANBASE (256 * NOUT * KK)
#define VARBASE  (MEANBASE + 256 * NOUT * KK * 32)

__device__ __forceinline__ float sigf(float x) { return 1.0f / (1.0f + expf(-x)); }

// --------------------------- one-time weight pack ---------------------------
__global__ __launch_bounds__(256) void prep_pack(
    const float* __restrict__ W_ih, const float* __restrict__ W_hh,
    const float* __restrict__ b_ih, const float* __restrict__ b_hh,
    const float* __restrict__ W1,   const float* __restrict__ W2,
    const float* __restrict__ W3,   float* __restrict__ ws)
{
    const int idx = blockIdx.x * 256 + threadIdx.x;
    if (idx < 65536) {
        int k = idx >> 8, u = idx & 255;
        float4 v;
        v.x = W_hh[(0 * 256 + u) * 256 + k];
        v.y = W_hh[(1 * 256 + u) * 256 + k];
        v.z = W_hh[(2 * 256 + u) * 256 + k];
        v.w = W_hh[(3 * 256 + u) * 256 + k];
        ((float4*)(ws + OFF_WHH))[idx] = v;
    } else if (idx < 74496) {
        int r = idx - 65536;
        int j = r >> 8, u = r & 255;
        float4 v;
        v.x = W_ih[(0 * 256 + u) * 35 + j];
        v.y = W_ih[(1 * 256 + u) * 35 + j];
        v.z = W_ih[(2 * 256 + u) * 35 + j];
        v.w = W_ih[(3 * 256 + u) * 35 + j];
        ((float4*)(ws + OFF_WIH))[r] = v;
    } else if (idx < 74752) {
        int u = idx - 74496;
        float4 v;
        v.x = b_ih[0 * 256 + u] + b_hh[0 * 256 + u];
        v.y = b_ih[1 * 256 + u] + b_hh[1 * 256 + u];
        v.z = b_ih[2 * 256 + u] + b_hh[2 * 256 + u];
        v.w = b_ih[3 * 256 + u] + b_hh[3 * 256 + u];
        ((float4*)(ws + OFF_BG))[u] = v;
    } else if (idx < 107520) {
        int r = idx - 74752;
        int k = r >> 7, c = r & 127;
        if (c < 100) ws[OFF_W1T + k * 128 + c] = W1[c * 256 + k];
    } else if (idx < 120320) {
        int r = idx - 107520;
        int k = r >> 7, c = r & 127;
        if (c < 100) ws[OFF_W2T + k * 128 + c] = W2[c * 100 + k];
    } else if (idx < 139520) {
        int r = idx - 120320;
        int k = r / 192, c = r - k * 192;
        if (c < 170) ws[OFF_W3T + k * 192 + c] = W3[c * 100 + k];
    }
}

// ------------------------------ persistent kernel ---------------------------
__global__ __launch_bounds__(512, 1) void mdn_rnn_persist(
    const float* __restrict__ x,
    const float* __restrict__ b1, const float* __restrict__ b2,
    const float* __restrict__ b3,
    float* __restrict__ ws, float* __restrict__ out)
{
    __shared__ float4 wlds4[4360];      // W_hh slice: k*17 + ul + (k>>5)
    __shared__ float4 xlds4[595];       // W_ih slice: j*17 + ul
    __shared__ float4 bg[16];
    __shared__ float  hlds[4096];       // h_s: [k][16], quad-col XOR swizzle
    __shared__ float  xst[2][700];      // x ping-pong [j][20]
    __shared__ float4 p4[2176];         // LSTM partials (kq*16+ul)*17 + b
    __shared__ float  hid1L[2][104];
    __shared__ float  hid2L[2][104];
    __shared__ float  oL[2][176];
    __shared__ float  cvbuf[80];        // coeff/var staging [8t][10]

    const int tid = threadIdx.x;
    const int wg  = blockIdx.x;
    const int ut  = wg >> 4;            // unit tile / cluster member
    const int g   = wg & 15;            // batch group / cluster id
    const int u0  = ut * 16;
    const int b0  = g * 16;
    const int bhead = b0 + ut;          // this WG's head batch

    // LSTM k-loop mapping (tid < 256)
    const int ul = tid & 15;
    const int kq = (tid >> 4) & 7;
    const int bh = (tid >> 7) & 1;
    // stage mapping (all 512)
    const int su = tid >> 1, shf = tid & 1;
    // x prefetch mapping (tid < 280)
    const int e0 = tid * 2,  pb0 = e0 / 35, pj0 = e0 - pb0 * 35;
    const int e1 = e0 + 1,   pb1 = e1 / 35, pj1 = e1 - pb1 * 35;

    const float4* Wg4 = (const float4*)(ws + OFF_WHH);
    const float4* Wx4 = (const float4*)(ws + OFF_WIH);
    const float4* Bg4 = (const float4*)(ws + OFF_BG);
    const float*  W1T = ws + OFF_W1T;
    const float*  W2T = ws + OFF_W2T;
    const float*  W3T = ws + OFF_W3T;
    float* hbuf = ws + OFF_H;
    unsigned* flags = (unsigned*)(ws + OFF_FLG);

    // ---- one-time staging ----
    for (int i = tid; i < 4096; i += 512) {
        int k = i >> 4, uu = i & 15;
        wlds4[k * 17 + uu + (k >> 5)] = Wg4[k * 256 + u0 + uu];
    }
    for (int i = tid; i < 560; i += 512) {
        int j = i >> 4, uu = i & 15;
        xlds4[j * 17 + uu] = Wx4[j * 256 + u0 + uu];
    }
    if (tid < 16) bg[tid] = Bg4[u0 + tid];
    if (tid < 280) {
        xst[0][pj0 * 20 + pb0] = x[(size_t)(b0 + pb0) * 35840 + pj0];
        xst[0][pj1 * 20 + pb1] = x[(size_t)(b0 + pb1) * 35840 + pj1];
    }
    __syncthreads();

    float c_reg = 0.0f;

    for (int s = 0; s < 1027; ++s) {
        const int parC = s & 1;
        const int parN = parC ^ 1;

        // ================= A: local head roles (no h_s dependence) =========
        float xpf0 = 0.f, xpf1 = 0.f;
        const bool dopf = (s < 1022) && (tid < 280);
        if (dopf) {
            const float* xp = x + (size_t)(s + 1) * 35;
            xpf0 = xp[(size_t)(b0 + pb0) * 35840 + pj0];
            xpf1 = xp[(size_t)(b0 + pb1) * 35840 + pj1];
        }
        if (s >= 2 && s <= 1024 && tid < 100) {              // L2
            float a = b2[tid];
            #pragma unroll 5
            for (int k = 0; k < 100; ++k)
                a = fmaf(W2T[k * 128 + tid], hid1L[parN][k], a);
            hid2L[parC][tid] = fmaxf(a, 0.f);
        }
        if (s >= 3 && s <= 1025 && tid >= 128 && tid < 298) { // L3
            const int ch = tid - 128;
            float a = b3[ch];
            #pragma unroll 5
            for (int k = 0; k < 100; ++k)
                a = fmaf(W3T[k * 192 + ch], hid2L[parN][k], a);
            oL[parC][ch] = a;
        }
        if (s >= 4 && tid >= 298 && tid < 468) {              // FIN compute
            const int lf = tid - 298;
            const int t  = s - 4;
            float m5 = oL[parN][0];
            #pragma unroll
            for (int k = 1; k < KK; ++k) m5 = fmaxf(m5, oL[parN][k]);
            float den = 0.f;
            #pragma unroll
            for (int k = 0; k < KK; ++k) den += expf(oL[parN][k] - m5);
            float v = oL[parN][lf];
            if (lf < KK) {
                cvbuf[(t & 7) * 10 + lf] = expf(v - m5) / den;
            } else if (lf < 2 * KK) {
                cvbuf[(t & 7) * 10 + lf] = expf(v);
            } else {
                out[MEANBASE + ((size_t)bhead * NOUT + t) * 160 + (lf - 10)] = v;
            }
        }
        __syncthreads();  // sync1

        // ================= A2: coeff/var flush + poll ======================
        if (s >= 4) {
            const int t = s - 4;
            if ((t & 7) == 7 || t == 1022) {
                const int n = (t & 7) + 1, t0 = t - n + 1;
                if (tid < 5 * n) {
                    out[(size_t)bhead * 5115 + t0 * 5 + tid] =
                        cvbuf[((t0 + tid / 5) & 7) * 10 + (tid % 5)];
                } else if (tid >= 40 && tid < 40 + 5 * n) {
                    const int f = tid - 40;
                    out[VARBASE + (size_t)bhead * 5115 + t0 * 5 + f] =
                        cvbuf[((t0 + f / 5) & 7) * 10 + 5 + (f % 5)];
                }
            }
        }
        if (s >= 1 && s <= 1023 && tid < 16) {
            const unsigned tgt = (unsigned)s;
            while (__hip_atomic_load(&flags[g * 16 + tid], __ATOMIC_RELAXED,
                                     __HIP_MEMORY_SCOPE_AGENT) < tgt)
                __builtin_amdgcn_s_sleep(1);
        }
        __syncthreads();  // sync2

        // ================= C: stage h_s global -> LDS (swizzled) ===========
        if (s <= 1023) {
            const unsigned long long* src = (const unsigned long long*)
                (hbuf + parC * 65536 + su * 256 + b0 + shf * 8);
            unsigned long long v[4];
            #pragma unroll
            for (int i = 0; i < 4; ++i)
                v[i] = __hip_atomic_load(src + i, __ATOMIC_RELAXED,
                                         __HIP_MEMORY_SCOPE_AGENT);
            const int qb = su >> 5;
            #pragma unroll
            for (int i = 0; i < 4; ++i) {
                const int c = shf * 8 + i * 2;
                const int q = (((c >> 2) + qb) & 3);
                float2 f2;
                f2.x = __uint_as_float((unsigned)v[i]);
                f2.y = __uint_as_float((unsigned)(v[i] >> 32));
                *(float2*)&hlds[su * 16 + q * 4 + (c & 3)] = f2;
            }
        }
        __syncthreads();  // sync3

        // ================= D: LSTM partials + L1 ===========================
        if (s <= 1022 && tid < 256) {
            float4 acc[8];
            #pragma unroll
            for (int j = 0; j < 8; ++j) acc[j] = make_float4(0.f, 0.f, 0.f, 0.f);
            const int q0 = ((bh * 2) + kq) & 3;
            const int q1 = ((bh * 2 + 1) + kq) & 3;
            const int kb = kq * 32;
            #pragma unroll 8
            for (int kk = 0; kk < 32; ++kk) {
                const int k = kb + kk;
                float4 w  = wlds4[k * 17 + ul + kq];
                float4 h0 = *(const float4*)&hlds[k * 16 + q0 * 4];
                float4 h1 = *(const float4*)&hlds[k * 16 + q1 * 4];
                acc[0].x = fmaf(w.x, h0.x, acc[0].x); acc[0].y = fmaf(w.y, h0.x, acc[0].y);
                acc[0].z = fmaf(w.z, h0.x, acc[0].z); acc[0].w = fmaf(w.w, h0.x, acc[0].w);
                acc[1].x = fmaf(w.x, h0.y, acc[1].x); acc[1].y = fmaf(w.y, h0.y, acc[1].y);
                acc[1].z = fmaf(w.z, h0.y, acc[1].z); acc[1].w = fmaf(w.w, h0.y, acc[1].w);
                acc[2].x = fmaf(w.x, h0.z, acc[2].x); acc[2].y = fmaf(w.y, h0.z, acc[2].y);
                acc[2].z = fmaf(w.z, h0.z, acc[2].z); acc[2].w = fmaf(w.w, h0.z, acc[2].w);
                acc[3].x = fmaf(w.x, h0.w, acc[3].x); acc[3].y = fmaf(w.y, h0.w, acc[3].y);
                acc[3].z = fmaf(w.z, h0.w, acc[3].z); acc[3].w = fmaf(w.w, h0.w, acc[3].w);
                acc[4].x = fmaf(w.x, h1.x, acc[4].x); acc[4].y = fmaf(w.y, h1.x, acc[4].y);
                acc[4].z = fmaf(w.z, h1.x, acc[4].z); acc[4].w = fmaf(w.w, h1.x, acc[4].w);
                acc[5].x = fmaf(w.x, h1.y, acc[5].x); acc[5].y = fmaf(w.y, h1.y, acc[5].y);
                acc[5].z = fmaf(w.z, h1.y, acc[5].z); acc[5].w = fmaf(w.w, h1.y, acc[5].w);
                acc[6].x = fmaf(w.x, h1.z, acc[6].x); acc[6].y = fmaf(w.y, h1.z, acc[6].y);
                acc[6].z = fmaf(w.z, h1.z, acc[6].z); acc[6].w = fmaf(w.w, h1.z, acc[6].w);
                acc[7].x = fmaf(w.x, h1.w, acc[7].x); acc[7].y = fmaf(w.y, h1.w, acc[7].y);
                acc[7].z = fmaf(w.z, h1.w, acc[7].z); acc[7].w = fmaf(w.w, h1.w, acc[7].w);
            }
            const float* xsrc = xst[parC];
            const int joff = (kq < 3) ? kq * 5 : 15 + (kq - 3) * 4;
            const int jcnt = (kq < 3) ? 5 : 4;
            for (int jj = 0; jj < jcnt; ++jj) {
                const int j = joff + jj;
                float4 w  = xlds4[j * 17 + ul];
                float4 x0 = *(const float4*)&xsrc[j * 20 + bh * 8];
                float4 x1 = *(const float4*)&xsrc[j * 20 + bh * 8 + 4];
                acc[0].x = fmaf(w.x, x0.x, acc[0].x); acc[0].y = fmaf(w.y, x0.x, acc[0].y);
                acc[0].z = fmaf(w.z, x0.x, acc[0].z); acc[0].w = fmaf(w.w, x0.x, acc[0].w);
                acc[1].x = fmaf(w.x, x0.y, acc[1].x); acc[1].y = fmaf(w.y, x0.y, acc[1].y);
                acc[1].z = fmaf(w.z, x0.y, acc[1].z); acc[1].w = fmaf(w.w, x0.y, acc[1].w);
                acc[2].x = fmaf(w.x, x0.z, acc[2].x); acc[2].y = fmaf(w.y, x0.z, acc[2].y);
                acc[2].z = fmaf(w.z, x0.z, acc[2].z); acc[2].w = fmaf(w.w, x0.z, acc[2].w);
                acc[3].x = fmaf(w.x, x0.w, acc[3].x); acc[3].y = fmaf(w.y, x0.w, acc[3].y);
                acc[3].z = fmaf(w.z, x0.w, acc[3].z); acc[3].w = fmaf(w.w, x0.w, acc[3].w);
                acc[4].x = fmaf(w.x, x1.x, acc[4].x); acc[4].y = fmaf(w.y, x1.x, acc[4].y);
                acc[4].z = fmaf(w.z, x1.x, acc[4].z); acc[4].w = fmaf(w.w, x1.x, acc[4].w);
                acc[5].x = fmaf(w.x, x1.y, acc[5].x); acc[5].y = fmaf(w.y, x1.y, acc[5].y);
                acc[5].z = fmaf(w.z, x1.y, acc[5].z); acc[5].w = fmaf(w.w, x1.y, acc[5].w);
                acc[6].x = fmaf(w.x, x1.z, acc[6].x); acc[6].y = fmaf(w.y, x1.z, acc[6].y);
                acc[6].z = fmaf(w.z, x1.z, acc[6].z); acc[6].w = fmaf(w.w, x1.z, acc[6].w);
                acc[7].x = fmaf(w.x, x1.w, acc[7].x); acc[7].y = fmaf(w.y, x1.w, acc[7].y);
                acc[7].z = fmaf(w.z, x1.w, acc[7].z); acc[7].w = fmaf(w.w, x1.w, acc[7].w);
            }
            const int rb = (kq * 16 + ul) * 17 + bh * 8;
            #pragma unroll
            for (int j = 0; j < 8; ++j) p4[rb + j] = acc[j];
        }
        if (s >= 1 && s <= 1023 && tid >= 256 && tid < 356) {  // L1
            const int ch = tid - 256;
            float a = b1[ch];
            #pragma unroll 8
            for (int k = 0; k < 256; ++k) {
                const int q = (((ut >> 2) + (k >> 5)) & 3);
                float hv = hlds[k * 16 + q * 4 + (ut & 3)];
                a = fmaf(W1T[k * 128 + ch], hv, a);
            }
            hid1L[parC][ch] = fmaxf(a, 0.f);
        }
        __syncthreads();  // sync4

        // ================= E: finalize LSTM, store h, xst ==================
        if (s <= 1022 && tid < 256) {
            const int fu = tid >> 4, fb = tid & 15;
            float4 gv = bg[fu];
            #pragma unroll
            for (int k2 = 0; k2 < 8; ++k2) {
                float4 p = p4[(k2 * 16 + fu) * 17 + fb];
                gv.x += p.x; gv.y += p.y; gv.z += p.z; gv.w += p.w;
            }
            float iv = sigf(gv.x), fv = sigf(gv.y);
            float gg = tanhf(gv.z), ov = sigf(gv.w);
            c_reg = fv * c_reg + iv * gg;
            float hval = ov * tanhf(c_reg);
            __hip_atomic_store(hbuf + parN * 65536 + (u0 + fu) * 256 + b0 + fb,
                               hval, __ATOMIC_RELAXED, __HIP_MEMORY_SCOPE_AGENT);
        }
        if (dopf) {
            xst[parN][pj0 * 20 + pb0] = xpf0;
            xst[parN][pj1 * 20 + pb1] = xpf1;
        }
        __syncthreads();  // sync5: drains vmcnt -> h stores complete
        if (s <= 1022 && tid == 0)
            __hip_atomic_store(&flags[g * 16 + ut], (unsigned)(s + 1),
                               __ATOMIC_RELAXED, __HIP_MEMORY_SCOPE_AGENT);
    }
}

extern "C" void kernel_launch(void* const* d_in, const int* in_sizes, int n_in,
                              void* d_out, int out_size, void* d_ws, size_t ws_size,
                              hipStream_t stream)
{
    const float* x    = (const float*)d_in[0];
    const float* W_ih = (const float*)d_in[1];
    const float* W_hh = (const float*)d_in[2];
    const float* b_ih = (const float*)d_in[3];
    const float* b_hh = (const float*)d_in[4];
    const float* W1   = (const float*)d_in[5];
    const float* b1   = (const float*)d_in[6];
    const float* W2   = (const float*)d_in[7];
    const float* b2   = (const float*)d_in[8];
    const float* W3   = (const float*)d_in[9];
    const float* b3   = (const float*)d_in[10];
    float* out = (float*)d_out;
    float* ws  = (float*)d_ws;

    hipMemsetAsync(ws + OFF_H,   0, 65536 * sizeof(float), stream);   // h_0 = 0
    hipMemsetAsync(ws + OFF_FLG, 0, 256 * sizeof(unsigned), stream);  // flags
    prep_pack<<<545, 256, 0, stream>>>(W_ih, W_hh, b_ih, b_hh, W1, W2, W3, ws);
    mdn_rnn_persist<<<256, 512, 0, stream>>>(x, b1, b2, b3, ws, out);
}